// Round 14
// baseline (62.242 us; speedup 1.0000x reference)
//
#include <hip/hip_runtime.h>
#include <hip/hip_fp16.h>

// Problem constants (reference: B,N,D,H,C = 4,512,128,128,3)
#define B_ 4
#define N_ 512
#define D_ 128
#define H_ 128
#define C_ 3

#define NEG_LOG2E   (-1.4426950408889634f)
#define NEG_HALF_LN2 (-0.34657359027997264f)   // -0.5 * ln(2)

typedef _Float16 half8  __attribute__((ext_vector_type(8)));
typedef _Float16 half4v __attribute__((ext_vector_type(4)));
typedef _Float16 half2v __attribute__((ext_vector_type(2)));

__device__ __forceinline__ float exp2_fast(float x) {
    return __builtin_amdgcn_exp2f(x);   // raw v_exp_f32 (2^x)
}

// Projections stored PRE-SCALED by -log2e in f16, PLUS their exp2 in f16:
//   At[row][h] = f16(-log2e * (dot(h[row], W1[h][0:128]) + b1[h]))   EAt = 2^At
//   Bt[row][h] = f16(-log2e *  dot(h[row], W1[h][128:256]))          EBt = 2^Bt
__global__ __launch_bounds__(256) void proj_gemm(
    const float* __restrict__ hd, const float* __restrict__ W1,
    const float* __restrict__ b1,
    _Float16* __restrict__ At,  _Float16* __restrict__ Bt,
    _Float16* __restrict__ EAt, _Float16* __restrict__ EBt)
{
    __shared__ float hsT[64][36];   // [k][m]
    __shared__ float wt [64][68];   // [k][o]
    const int m0      = blockIdx.x * 32;
    const int by      = blockIdx.y;        // 0..3
    const int halfSel = by >> 1;           // 0 -> At, 1 -> Bt
    const int wrow0   = (by & 1) * 64;     // W1 row base (== output h-col base)

    const int t  = threadIdx.x;
    const int r  = t >> 4, c4 = t & 15;
    const int tx = t & 15, ty = t >> 4;

    float acc[2][4] = {};

    for (int kc = 0; kc < 2; ++kc) {
        if (kc) __syncthreads();
        #pragma unroll
        for (int i = 0; i < 2; ++i) {
            const int m = r + 16 * i;
            float4 v = *(const float4*)&hd[(m0 + m) * D_ + kc * 64 + 4 * c4];
            hsT[4 * c4 + 0][m] = v.x; hsT[4 * c4 + 1][m] = v.y;
            hsT[4 * c4 + 2][m] = v.z; hsT[4 * c4 + 3][m] = v.w;
        }
        #pragma unroll
        for (int i = 0; i < 4; ++i) {
            const int o = r + 16 * i;
            float4 v = *(const float4*)&W1[(wrow0 + o) * (2 * D_) + halfSel * D_ + kc * 64 + 4 * c4];
            wt[4 * c4 + 0][o] = v.x; wt[4 * c4 + 1][o] = v.y;
            wt[4 * c4 + 2][o] = v.z; wt[4 * c4 + 3][o] = v.w;
        }
        __syncthreads();
        #pragma unroll 8
        for (int k = 0; k < 64; ++k) {
            float2 a  = *(const float2*)&hsT[k][2 * ty];
            float4 bv = *(const float4*)&wt [k][4 * tx];
            acc[0][0] = fmaf(a.x, bv.x, acc[0][0]); acc[0][1] = fmaf(a.x, bv.y, acc[0][1]);
            acc[0][2] = fmaf(a.x, bv.z, acc[0][2]); acc[0][3] = fmaf(a.x, bv.w, acc[0][3]);
            acc[1][0] = fmaf(a.y, bv.x, acc[1][0]); acc[1][1] = fmaf(a.y, bv.y, acc[1][1]);
            acc[1][2] = fmaf(a.y, bv.z, acc[1][2]); acc[1][3] = fmaf(a.y, bv.w, acc[1][3]);
        }
    }

    _Float16* dst  = halfSel ? Bt  : At;
    _Float16* edst = halfSel ? EBt : EAt;
    const int ocol = wrow0 + 4 * tx;
    float biasv[4] = {0.f, 0.f, 0.f, 0.f};
    if (!halfSel) {
        float4 bb = *(const float4*)&b1[ocol];
        biasv[0] = bb.x; biasv[1] = bb.y; biasv[2] = bb.z; biasv[3] = bb.w;
    }
    #pragma unroll
    for (int i = 0; i < 2; ++i) {
        half4v o, ee;
        #pragma unroll
        for (int k = 0; k < 4; ++k) {
            o[k]  = (_Float16)((acc[i][k] + biasv[k]) * NEG_LOG2E);
            ee[k] = (_Float16)exp2_fast((float)o[k]);   // E = 2^y, consistent with y_f16
        }
        const size_t off = (size_t)(m0 + 2 * ty + i) * H_ + ocol;
        *(half4v*)&dst[off]  = o;    // 8B stores
        *(half4v*)&edst[off] = ee;
    }
}

// LDS-FREE pair kernel. One WAVE (64 threads) per (batch, 4-i-rows x 64-j) tile,
// triangle-enumerated: jt in 0..7 (64 j's each), it counts min(16*(jt+1),128).
// Lane = j. Per h-chunk of 8: j-side y/e loaded coalesced into registers
// (reused across 4 i); i-side loaded wave-uniform (same addr -> L1 broadcast,
// data is L2-hot: 2 MB total). Exp-factorized f16 math in explicit half2
// (v_pk_*), final rcp in f32. Each pair computed once, written to (i,j) and
// (j,i); lanes with j < i (diagonal-straddling tiles only) skip the write.
__global__ __launch_bounds__(64, 4) void pair_kernel(
    const _Float16* __restrict__ At,  const _Float16* __restrict__ Bt,
    const _Float16* __restrict__ EAt, const _Float16* __restrict__ EBt,
    const float* __restrict__ W2, const float* __restrict__ b2,
    float* __restrict__ out)
{
    const int b = blockIdx.y;
    int x = blockIdx.x;
    int jt = 0;
    for (;;) {                      // uniform decode, <= 8 iters
        int cnt = 16 * (jt + 1); if (cnt > 128) cnt = 128;
        if (x < cnt) break;
        x -= cnt; ++jt;
    }
    const int i0 = x * 4;
    const int j  = jt * 64 + (int)threadIdx.x;

    const size_t jbase = ((size_t)(b * N_) + j)  * H_;
    const size_t ibase = ((size_t)(b * N_) + i0) * H_;

    float acc[4][3] = {};

    for (int ch = 0; ch < 16; ++ch) {
        const int hb = ch * 8;
        const half8 yAj = *(const half8*)&At [jbase + hb];
        const half8 yBj = *(const half8*)&Bt [jbase + hb];
        const half8 eAj = *(const half8*)&EAt[jbase + hb];
        const half8 eBj = *(const half8*)&EBt[jbase + hb];
        const half2v* yAj2p = (const half2v*)&yAj;
        const half2v* yBj2p = (const half2v*)&yBj;
        const half2v* eAj2p = (const half2v*)&eAj;
        const half2v* eBj2p = (const half2v*)&eBj;

        float4 w0a = *(const float4*)&W2[hb],          w0b = *(const float4*)&W2[hb + 4];
        float4 w1a = *(const float4*)&W2[H_ + hb],     w1b = *(const float4*)&W2[H_ + hb + 4];
        float4 w2a = *(const float4*)&W2[2 * H_ + hb], w2b = *(const float4*)&W2[2 * H_ + hb + 4];
        const float w0[8] = {w0a.x, w0a.y, w0a.z, w0a.w, w0b.x, w0b.y, w0b.z, w0b.w};
        const float w1[8] = {w1a.x, w1a.y, w1a.z, w1a.w, w1b.x, w1b.y, w1b.z, w1b.w};
        const float w2[8] = {w2a.x, w2a.y, w2a.z, w2a.w, w2b.x, w2b.y, w2b.z, w2b.w};

        #pragma unroll
        for (int ii = 0; ii < 4; ++ii) {
            const size_t ir = ibase + (size_t)ii * H_ + hb;   // wave-uniform address
            const half8 yAi = *(const half8*)&At [ir];
            const half8 yBi = *(const half8*)&Bt [ir];
            const half8 eAi = *(const half8*)&EAt[ir];
            const half8 eBi = *(const half8*)&EBt[ir];
            const half2v* yAi2p = (const half2v*)&yAi;
            const half2v* yBi2p = (const half2v*)&yBi;
            const half2v* eAi2p = (const half2v*)&eAi;
            const half2v* eBi2p = (const half2v*)&eBi;

            #pragma unroll
            for (int q = 0; q < 4; ++q) {
                half2v y1 = yAi2p[q] + yBj2p[q];     // v_pk_add_f16
                half2v y2 = yAj2p[q] + yBi2p[q];
                half2v e1 = eAi2p[q] * eBj2p[q];     // v_pk_mul_f16
                half2v e2 = eAj2p[q] * eBi2p[q];
                half2v d1 = e1 + (_Float16)1.0f;
                half2v d2 = e2 + (_Float16)1.0f;
                half2v pp  = d1 * d2;
                half2v num = y1 * d2 + y2 * d1;      // pk_mul + pk_fma

                #pragma unroll
                for (int e = 0; e < 2; ++e) {
                    const float s = (float)num[e] * __builtin_amdgcn_rcpf((float)pp[e]);
                    const int hh = 2 * q + e;
                    acc[ii][0] = fmaf(s, w0[hh], acc[ii][0]);
                    acc[ii][1] = fmaf(s, w1[hh], acc[ii][1]);
                    acc[ii][2] = fmaf(s, w2[hh], acc[ii][2]);
                }
            }
        }
    }

    const float b20 = b2[0], b21 = b2[1], b22 = b2[2];
    #pragma unroll
    for (int ii = 0; ii < 4; ++ii) {
        const int i = i0 + ii;
        if (j >= i) {                      // each unordered pair exactly once
            const float o0 = fmaf(NEG_HALF_LN2, acc[ii][0], b20);
            const float o1 = fmaf(NEG_HALF_LN2, acc[ii][1], b21);
            const float o2 = fmaf(NEG_HALF_LN2, acc[ii][2], b22);
            float* p1 = out + ((size_t)(b * N_ + i) * N_ + j) * C_;
            float* p2 = out + ((size_t)(b * N_ + j) * N_ + i) * C_;
            p1[0] = o0; p1[1] = o1; p1[2] = o2;
            p2[0] = o0; p2[1] = o1; p2[2] = o2;   // diagonal: same thread, same value
        }
    }
}

extern "C" void kernel_launch(void* const* d_in, const int* in_sizes, int n_in,
                              void* d_out, int out_size, void* d_ws, size_t ws_size,
                              hipStream_t stream) {
    const float* hd = (const float*)d_in[0];
    const float* W1 = (const float*)d_in[1];
    const float* b1 = (const float*)d_in[2];
    const float* W2 = (const float*)d_in[3];
    const float* b2 = (const float*)d_in[4];
    float* out = (float*)d_out;

    _Float16* At  = (_Float16*)d_ws;             // 4 x [B*N][H] f16 = 2 MiB total
    _Float16* Bt  = At  + B_ * N_ * H_;
    _Float16* EAt = Bt  + B_ * N_ * H_;
    _Float16* EBt = EAt + B_ * N_ * H_;

    proj_gemm<<<dim3((B_ * N_) / 32, 4), dim3(256), 0, stream>>>(hd, W1, b1, At, Bt, EAt, EBt);

    // triangle tiles: jt=0..7 (64 j each), it-count = min(16*(jt+1),128); sum = 576
    pair_kernel<<<dim3(576, B_), dim3(64), 0, stream>>>(At, Bt, EAt, EBt, W2, b2, out);
}